// Round 11
// baseline (143.024 us; speedup 1.0000x reference)
//
#include <hip/hip_runtime.h>
#include <cstdint>

#define IN_F 4096
#define OUT_F 11008
#define Q_OUT 5504
#define GROUP 128
#define BATCH 32

#define KBS 8            // k-splits (gridDim.y)
#define GPB 4            // quant groups per block
#define NCH 8            // 64-k chunks per block (K=512)
#define BN 64            // output cols per block
#define BST 18           // b_lds dword stride per n-row: 16 data + 2 pad
#define REPS 6           // DIAGNOSTIC: reps per dispatch; rep 0 -> out, 1..5 -> scratch

typedef int   i32x4 __attribute__((ext_vector_type(4)));
typedef float f32x4 __attribute__((ext_vector_type(4)));

// ---------------------------------------------------------------------------
// Prep kernel, two roles by blockIdx:
//  blocks 0..31: row m: maxabs -> delta[m]; quantize x to i8 in MFMA A-frag
//    order; per-group row sums Sx[g][m] (i32, exact).
//  blocks 32..32+86*REPS-1: region init: region 0 = out, regions 1..5 =
//    scratch (bias pattern) — re-initialized EVERY launch so replays are
//    identical and the gemm's scratch atomics are deterministic per launch.
// ---------------------------------------------------------------------------
__global__ __launch_bounds__(256)
void prep_kernel(const float* __restrict__ x,
                 const float* __restrict__ bias,
                 uint4* __restrict__ xq,     // 8192 slots of 16 i8
                 int*   __restrict__ Sx,     // [32 g][32 m]
                 float* __restrict__ delta,  // [32]
                 float* __restrict__ out,
                 float* __restrict__ scratch)
{
    const int t = threadIdx.x;
    if (blockIdx.x >= 32) {
        const int bi     = blockIdx.x - 32;
        const int region = bi / 86;           // 0..REPS-1
        const int rb     = bi % 86;
        float* dst = (region == 0) ? out
                   : scratch + (size_t)(region - 1) * ((size_t)BATCH * OUT_F);
        const int base = rb * 4096 + t * 16;
        #pragma unroll
        for (int i = 0; i < 4; ++i)
            *reinterpret_cast<float4*>(dst + base + i * 4) =
                *reinterpret_cast<const float4*>(bias + ((base + i * 4) % OUT_F));
        return;
    }
    const int m = blockIdx.x;
    const float* xr = x + (size_t)m * IN_F + t * 16;  // thread owns k=16t..16t+15
    float4 v[4];
    #pragma unroll
    for (int i = 0; i < 4; ++i) v[i] = reinterpret_cast<const float4*>(xr)[i];

    float lm = 0.f;
    #pragma unroll
    for (int i = 0; i < 4; ++i) {
        lm = fmaxf(lm, fmaxf(fmaxf(fabsf(v[i].x), fabsf(v[i].y)),
                             fmaxf(fabsf(v[i].z), fabsf(v[i].w))));
    }
    #pragma unroll
    for (int d = 32; d; d >>= 1) lm = fmaxf(lm, __shfl_xor(lm, d));
    __shared__ float wred[4];
    if ((t & 63) == 0) wred[t >> 6] = lm;
    __syncthreads();
    const float mx  = fmaxf(fmaxf(wred[0], wred[1]), fmaxf(wred[2], wred[3]));
    const float inv = mx > 0.f ? 127.0f / mx : 0.f;

    int q[16];
    #pragma unroll
    for (int i = 0; i < 4; ++i) {
        q[i * 4 + 0] = __float2int_rn(v[i].x * inv);
        q[i * 4 + 1] = __float2int_rn(v[i].y * inv);
        q[i * 4 + 2] = __float2int_rn(v[i].z * inv);
        q[i * 4 + 3] = __float2int_rn(v[i].w * inv);
    }
    uint4 w;
    uint* wp = reinterpret_cast<uint*>(&w);
    #pragma unroll
    for (int i = 0; i < 4; ++i)
        wp[i] = (q[i*4] & 255) | ((q[i*4+1] & 255) << 8) |
                ((q[i*4+2] & 255) << 16) | ((q[i*4+3] & 255) << 24);
    // slot = S*128 + f*64 + kg*16 + (m&15);  S=t>>2, kg=t&3, f=m>>4
    xq[(t >> 2) * 128 + (m >> 4) * 64 + (t & 3) * 16 + (m & 15)] = w;

    int psum = 0;
    #pragma unroll
    for (int i = 0; i < 16; ++i) psum += q[i];
    #pragma unroll
    for (int d = 4; d; d >>= 1) psum += __shfl_down(psum, d, 8);
    if ((t & 7) == 0) Sx[(t >> 3) * 32 + m] = psum;   // g = t>>3
    if (t == 0) delta[m] = mx * (1.0f / 127.0f);
}

// ---------------------------------------------------------------------------
// DIAGNOSTIC mega-GEMM: the exact r5 kernel body (28.4 us pipeline, best
// known), executed REPS times per dispatch. rep 0 = real output (atomics to
// out); reps 1..5 = identical work targeting scratch. Opaque per-rep pointer
// offsets (inline asm "+s") defeat cross-rep load CSE. Purpose: (1) the
// dispatch becomes longer than the harness's 52us ws-poison fills, so the
// gemm's PMC counters finally appear in the top-5; (2) gemm_iso =
// dispatch_dur / REPS; (3) prep+launch overhead = dur_us - dispatch_dur.
// ---------------------------------------------------------------------------
__global__ __launch_bounds__(256, 4)
void int4_gemm_i8(const uint4* __restrict__ xq,
                  const int*   __restrict__ qw,
                  const float* __restrict__ scales,
                  const int*   __restrict__ qz,
                  const int*   __restrict__ Sx,
                  const float* __restrict__ delta,
                  float*       __restrict__ out,
                  float*       __restrict__ scratch)
{
    const int tid  = threadIdx.x;
    const int lane = tid & 63;
    const int wid  = tid >> 6;
    const int nb   = blockIdx.x;          // 0..171
    const int kb   = blockIdx.y;          // 0..7
    const int g0   = kb * GPB;
    const int k0b  = g0 * GROUP;

    __shared__ uint4 a_lds[1024];         // 16 KB
    __shared__ int   b_lds[2][64 * BST];  // 2 x 4.5 KB

    const int cl  = lane & 15;
    const int kg  = lane >> 4;
    const int n   = nb * BN + wid * 16 + cl;
    const int shn = (cl & 1) * 4;

    // per-group constants (once; same as real kernel)
    int   zv[GPB];
    float sv[GPB];
    #pragma unroll
    for (int g = 0; g < GPB; ++g) {
        sv[g] = scales[(size_t)(g0 + g) * OUT_F + n];
        zv[g] = (qz[(size_t)(g0 + g) * Q_OUT + (n >> 1)] >> shn) & 15;
    }

    const int a16 = tid & 15;
    const int rk  = tid >> 4;

    // epilogue row-scales (once)
    float4 dl0 = *reinterpret_cast<const float4*>(delta + kg * 4);
    float4 dl1 = *reinterpret_cast<const float4*>(delta + 16 + kg * 4);
    const float dla[8] = { dl0.x, dl0.y, dl0.z, dl0.w, dl1.x, dl1.y, dl1.z, dl1.w };

    #pragma unroll 1
    for (int rep = 0; rep < REPS; ++rep) {
        size_t qoff = 0, aoff = 0, soff = 0;
        asm volatile("" : "+s"(qoff), "+s"(aoff), "+s"(soff));
        const int*   qwr = qw + qoff;
        const uint4* xqr = xq + aoff;
        const int*   Sxr = Sx + soff;
        float* dst = (rep == 0) ? out
                   : scratch + (size_t)(rep - 1) * ((size_t)BATCH * OUT_F);

        // guard LDS reuse across reps (all waves done reading prior rep)
        __builtin_amdgcn_s_barrier();

        // ---- A stage: kb's 1024 contiguous uint4 slots -> LDS, linear ----
        #pragma unroll
        for (int r = 0; r < 4; ++r) {
            const uint4* gp = xqr + (size_t)kb * 1024 + r * 256 + tid;
            __builtin_amdgcn_global_load_lds(
                (const __attribute__((address_space(1))) uint32_t*)gp,
                (__attribute__((address_space(3))) uint32_t*)&a_lds[r * 256 + wid * 64],
                16, 0, 0);
        }

        uint2 d[2][4];
        i32x4 acc_i[2] = {};
        f32x4 accf[2]  = {};
        int4  sx0v = {}, sx1v = {};

        auto LOADB = [&](int c, int set) {
            const int kr = k0b + c * 64 + 4 * rk;
            #pragma unroll
            for (int i = 0; i < 4; ++i)
                d[set][i] = *reinterpret_cast<const uint2*>(
                    qwr + (size_t)(kr + i) * Q_OUT + nb * 32 + 2 * a16);
        };
        auto WLDS = [&](int buf, int set) {
            #pragma unroll
            for (int j = 0; j < 2; ++j) {
                uint b0 = (j ? d[set][0].y : d[set][0].x) & 255u;
                uint b1 = (j ? d[set][1].y : d[set][1].x) & 255u;
                uint b2 = (j ? d[set][2].y : d[set][2].x) & 255u;
                uint b3 = (j ? d[set][3].y : d[set][3].x) & 255u;
                uint p  = b0 | (b1 << 8) | (b2 << 16) | (b3 << 24);
                const int nloc = 4 * a16 + 2 * j;
                b_lds[buf][(nloc + 0) * BST + rk] = (int)(p & 0x0F0F0F0Fu);
                b_lds[buf][(nloc + 1) * BST + rk] = (int)((p >> 4) & 0x0F0F0F0Fu);
            }
        };

        LOADB(0, 0);
        LOADB(1, 1);
        WLDS(0, 0);
        asm volatile("s_waitcnt vmcnt(0) lgkmcnt(0)" ::: "memory");
        __builtin_amdgcn_s_barrier();
        asm volatile("" ::: "memory");

        #pragma unroll
        for (int c = 0; c < NCH; ++c) {
            const int cur = c & 1;
            const int gl  = c >> 1;
            if (c + 2 < NCH) LOADB(c + 2, cur);   // d[cur] flushed at iter c-1
            if ((c & 1) == 0) {
                sx0v = *reinterpret_cast<const int4*>(Sxr + (g0 + gl) * 32 + kg * 4);
                sx1v = *reinterpret_cast<const int4*>(Sxr + (g0 + gl) * 32 + 16 + kg * 4);
            }

            const int* bp = &b_lds[cur][(wid * 16 + cl) * BST + 4 * kg];
            int2 qa = *reinterpret_cast<const int2*>(bp);
            int2 qb = *reinterpret_cast<const int2*>(bp + 2);
            i32x4 bv; bv[0] = qa.x; bv[1] = qa.y; bv[2] = qb.x; bv[3] = qb.y;

            uint4 a0 = a_lds[(c * 2 + 0) * 64 + lane];
            uint4 a1 = a_lds[(c * 2 + 1) * 64 + lane];
            acc_i[0] = __builtin_amdgcn_mfma_i32_16x16x64_i8(
                __builtin_bit_cast(i32x4, a0), bv, acc_i[0], 0, 0, 0);
            acc_i[1] = __builtin_amdgcn_mfma_i32_16x16x64_i8(
                __builtin_bit_cast(i32x4, a1), bv, acc_i[1], 0, 0, 0);

            if (c & 1) {
                const int   zz = zv[gl];
                const float ss = sv[gl];
                int sxa[8] = { sx0v.x, sx0v.y, sx0v.z, sx0v.w,
                               sx1v.x, sx1v.y, sx1v.z, sx1v.w };
                #pragma unroll
                for (int f = 0; f < 2; ++f)
                    #pragma unroll
                    for (int r = 0; r < 4; ++r) {
                        int tt = acc_i[f][r] - zz * sxa[f * 4 + r];
                        accf[f][r] = fmaf(ss, (float)tt, accf[f][r]);
                    }
                acc_i[0] = i32x4{0, 0, 0, 0};
                acc_i[1] = i32x4{0, 0, 0, 0};
            }

            if (c + 1 < NCH) {
                WLDS(cur ^ 1, cur ^ 1);
                asm volatile("s_waitcnt lgkmcnt(0)" ::: "memory");
                __builtin_amdgcn_s_barrier();
                asm volatile("" ::: "memory");
            }
        }

        // epilogue: C/D col=lane&15, row=(lane>>4)*4+reg; dst += delta_m*accf
        #pragma unroll
        for (int f = 0; f < 2; ++f)
            #pragma unroll
            for (int r = 0; r < 4; ++r) {
                const int m = f * 16 + kg * 4 + r;
                unsafeAtomicAdd(dst + (size_t)m * OUT_F + n,
                                dla[f * 4 + r] * accf[f][r]);
            }
    }
}

extern "C" void kernel_launch(void* const* d_in, const int* in_sizes, int n_in,
                              void* d_out, int out_size, void* d_ws, size_t ws_size,
                              hipStream_t stream)
{
    const float* inp    = (const float*)d_in[0];
    const int*   qw     = (const int*)d_in[1];
    const float* scales = (const float*)d_in[2];
    const int*   qz     = (const int*)d_in[3];
    const float* bias   = (const float*)d_in[4];
    float*       out    = (float*)d_out;

    uint4* xq      = (uint4*)d_ws;                          // 128 KB
    int*   Sx      = (int*)((char*)d_ws + 131072);          // 4 KB
    float* delta   = (float*)((char*)d_ws + 131072 + 4096); // 128 B
    float* scratch = (float*)((char*)d_ws + (1 << 20));     // (REPS-1) x 1.376 MB

    // blocks 0..31: quantize rows + Sx + delta; rest: init out + scratch regions
    prep_kernel<<<32 + 86 * REPS, 256, 0, stream>>>(inp, bias, xq, Sx, delta,
                                                    out, scratch);

    int4_gemm_i8<<<dim3(OUT_F / BN, KBS), 256, 0, stream>>>(
        xq, qw, scales, qz, Sx, delta, out, scratch);
}

// Round 12
// 39.909 us; speedup vs baseline: 3.5837x; 3.5837x over previous
//
#include <hip/hip_runtime.h>
#include <cstdint>

#define IN_F 4096
#define OUT_F 11008
#define Q_OUT 5504
#define GROUP 128
#define BATCH 32

#define KBS 8            // k-splits (gridDim.y)
#define GPB 4            // quant groups per block
#define NCH 8            // 64-k chunks per block (K=512)
#define BN 64            // output cols per block (16 per wave)
#define BST 18           // per-wave b_lds dword stride per n-row: 16 data + 2 pad

typedef int   i32x4 __attribute__((ext_vector_type(4)));
typedef float f32x4 __attribute__((ext_vector_type(4)));

// ---------------------------------------------------------------------------
// Prep kernel, two roles by blockIdx:
//  blocks 0..31: row m: maxabs -> delta[m]; quantize x to i8 in MFMA A-frag
//    order; per-group row sums Sx[g][m] (i32, exact).
//  blocks 32..117: out[m][n] = bias[n]  (16 floats/thread; gemm atomics add)
// ---------------------------------------------------------------------------
__global__ __launch_bounds__(256)
void prep_kernel(const float* __restrict__ x,
                 const float* __restrict__ bias,
                 uint4* __restrict__ xq,     // 8192 slots of 16 i8
                 int*   __restrict__ Sx,     // [32 g][32 m]
                 float* __restrict__ delta,  // [32]
                 float* __restrict__ out)
{
    const int t = threadIdx.x;
    if (blockIdx.x >= 32) {
        const int base = (blockIdx.x - 32) * 4096 + t * 16;
        #pragma unroll
        for (int i = 0; i < 4; ++i)
            *reinterpret_cast<float4*>(out + base + i * 4) =
                *reinterpret_cast<const float4*>(bias + ((base + i * 4) % OUT_F));
        return;
    }
    const int m = blockIdx.x;
    const float* xr = x + (size_t)m * IN_F + t * 16;  // thread owns k=16t..16t+15
    float4 v[4];
    #pragma unroll
    for (int i = 0; i < 4; ++i) v[i] = reinterpret_cast<const float4*>(xr)[i];

    float lm = 0.f;
    #pragma unroll
    for (int i = 0; i < 4; ++i) {
        lm = fmaxf(lm, fmaxf(fmaxf(fabsf(v[i].x), fabsf(v[i].y)),
                             fmaxf(fabsf(v[i].z), fabsf(v[i].w))));
    }
    #pragma unroll
    for (int d = 32; d; d >>= 1) lm = fmaxf(lm, __shfl_xor(lm, d));
    __shared__ float wred[4];
    if ((t & 63) == 0) wred[t >> 6] = lm;
    __syncthreads();
    const float mx  = fmaxf(fmaxf(wred[0], wred[1]), fmaxf(wred[2], wred[3]));
    const float inv = mx > 0.f ? 127.0f / mx : 0.f;

    int q[16];
    #pragma unroll
    for (int i = 0; i < 4; ++i) {
        q[i * 4 + 0] = __float2int_rn(v[i].x * inv);
        q[i * 4 + 1] = __float2int_rn(v[i].y * inv);
        q[i * 4 + 2] = __float2int_rn(v[i].z * inv);
        q[i * 4 + 3] = __float2int_rn(v[i].w * inv);
    }
    uint4 w;
    uint* wp = reinterpret_cast<uint*>(&w);
    #pragma unroll
    for (int i = 0; i < 4; ++i)
        wp[i] = (q[i*4] & 255) | ((q[i*4+1] & 255) << 8) |
                ((q[i*4+2] & 255) << 16) | ((q[i*4+3] & 255) << 24);
    // slot = S*128 + f*64 + kg*16 + (m&15);  S=t>>2, kg=t&3, f=m>>4
    xq[(t >> 2) * 128 + (m >> 4) * 64 + (t & 3) * 16 + (m & 15)] = w;

    int psum = 0;
    #pragma unroll
    for (int i = 0; i < 16; ++i) psum += q[i];
    #pragma unroll
    for (int d = 4; d; d >>= 1) psum += __shfl_down(psum, d, 8);
    if ((t & 7) == 0) Sx[(t >> 3) * 32 + m] = psum;   // g = t>>3
    if (t == 0) delta[m] = mx * (1.0f / 127.0f);
}

// ---------------------------------------------------------------------------
// GEMM, wave-autonomous: 4 waves/block, each wave owns 16 cols x 32 m x K=512
// with a PRIVATE LDS double-buffer slice -> ZERO s_barrier in the kernel.
// (r11 PMC: MfmaUtil 2%, VALUBusy 13%, HBM 31%, occupancy 34.5% -> the r5
//  structure was latency-bound on barrier lockstep, not on any pipe.)
// B: per wave per chunk, lane (rq=lane&15, ip=lane>>4) loads 4 rows x uint2
//    (rows 4rq.., ints 2ip..) of the wave's 32-B row segment; byte-transpose +
//    nibble-split -> 4 b32 writes into [16 n][18 dw] slice (2-way, free).
//    DS ops are wave-in-order; lgkmcnt(0) alone sequences dbuf reuse.
// A: i8 frags direct from global xq (L2-hot, r7-proven), 2-deep, refilled
//    AFTER MFMA consumption (r7 register-hazard discipline).
// Per group (2 chunks): acc_i32 -> accf += s*(D - z*Sx).
// Epilogue: out += delta_m * accf via unsafeAtomicAdd (out = bias by prep).
// ---------------------------------------------------------------------------
__global__ __launch_bounds__(256, 4)
void int4_gemm_i8(const uint4* __restrict__ xq,
                  const int*   __restrict__ qw,
                  const float* __restrict__ scales,
                  const int*   __restrict__ qz,
                  const int*   __restrict__ Sx,
                  const float* __restrict__ delta,
                  float*       __restrict__ out)
{
    const int tid  = threadIdx.x;
    const int lane = tid & 63;
    const int wid  = tid >> 6;            // 0..3
    const int nb   = blockIdx.x;          // 0..171
    const int kb   = blockIdx.y;          // 0..7
    const int g0   = kb * GPB;
    const int k0b  = g0 * GROUP;

    __shared__ int b_lds[4][2][16 * BST]; // per-wave slices, 9.2 KB total
    int (*bl)[16 * BST] = b_lds[wid];     // this wave's private dbuf

    const int cl  = lane & 15;
    const int kg  = lane >> 4;
    const int n   = nb * BN + wid * 16 + cl;
    const int shn = (cl & 1) * 4;

    // per-group constants
    int   zv[GPB];
    float sv[GPB];
    #pragma unroll
    for (int g = 0; g < GPB; ++g) {
        sv[g] = scales[(size_t)(g0 + g) * OUT_F + n];
        zv[g] = (qz[(size_t)(g0 + g) * Q_OUT + (n >> 1)] >> shn) & 15;
    }

    // B staging: rq = row-quad 0..15 (rows 4rq..4rq+3), ip = int-pair 0..3
    const int rq = lane & 15;
    const int ip = lane >> 4;

    uint2 d[2][4];                        // [set][row]
    uint4 A[2][2];                        // [set][f]
    i32x4 acc_i[2] = {};
    f32x4 accf[2]  = {};
    int4  sx0v = {}, sx1v = {};

    auto LOADB = [&](int c, int set) {
        const int kr = k0b + c * 64 + 4 * rq;
        #pragma unroll
        for (int i = 0; i < 4; ++i)
            d[set][i] = *reinterpret_cast<const uint2*>(
                qw + (size_t)(kr + i) * Q_OUT + nb * 32 + wid * 8 + 2 * ip);
    };
    auto LOADA = [&](int c, int set) {
        const uint4* ab = xq + (size_t)kb * 1024 + c * 128;
        A[set][0] = ab[lane];
        A[set][1] = ab[64 + lane];
    };
    auto WLDS = [&](int buf, int set) {
        #pragma unroll
        for (int j = 0; j < 2; ++j) {
            // vertical pack: byte j of rows 4rq..4rq+3, int word 2ip+j
            uint b0 = (j ? d[set][0].y : d[set][0].x) & 255u;
            uint b1 = (j ? d[set][1].y : d[set][1].x) & 255u;
            uint b2 = (j ? d[set][2].y : d[set][2].x) & 255u;
            uint b3 = (j ? d[set][3].y : d[set][3].x) & 255u;
            uint p  = b0 | (b1 << 8) | (b2 << 16) | (b3 << 24);
            const int nl = 4 * ip + 2 * j;        // n-local of low-nibble col
            bl[buf][(nl + 0) * BST + rq] = (int)(p & 0x0F0F0F0Fu);
            bl[buf][(nl + 1) * BST + rq] = (int)((p >> 4) & 0x0F0F0F0Fu);
        }
    };

    LOADB(0, 0);
    LOADA(0, 0);
    LOADB(1, 1);
    LOADA(1, 1);
    WLDS(0, 0);                           // compiler inserts vmcnt wait for set 0

    #pragma unroll
    for (int c = 0; c < NCH; ++c) {
        const int cur = c & 1;
        const int gl  = c >> 1;
        if (c + 2 < NCH) LOADB(c + 2, cur);   // d[cur] flushed by WLDS at c-1
        if ((c & 1) == 0) {   // group start: fetch Sx rows (L2-hot)
            sx0v = *reinterpret_cast<const int4*>(Sx + (g0 + gl) * 32 + kg * 4);
            sx1v = *reinterpret_cast<const int4*>(Sx + (g0 + gl) * 32 + 16 + kg * 4);
        }

        // wave-private dbuf: ds ops are in-order per wave; wait for WLDS(cur)
        asm volatile("s_waitcnt lgkmcnt(0)" ::: "memory");

        const int* bp = &bl[cur][cl * BST + 4 * kg];
        int2 qa = *reinterpret_cast<const int2*>(bp);
        int2 qb = *reinterpret_cast<const int2*>(bp + 2);
        i32x4 bv; bv[0] = qa.x; bv[1] = qa.y; bv[2] = qb.x; bv[3] = qb.y;

        acc_i[0] = __builtin_amdgcn_mfma_i32_16x16x64_i8(
            __builtin_bit_cast(i32x4, A[cur][0]), bv, acc_i[0], 0, 0, 0);
        acc_i[1] = __builtin_amdgcn_mfma_i32_16x16x64_i8(
            __builtin_bit_cast(i32x4, A[cur][1]), bv, acc_i[1], 0, 0, 0);

        // A prefetch AFTER consumption (same register set; r7 lesson)
        if (c + 2 < NCH) LOADA(c + 2, cur);

        if (c & 1) {          // group end: integer zero-point fixup, scale
            const int   zz = zv[gl];
            const float ss = sv[gl];
            int sxa[8] = { sx0v.x, sx0v.y, sx0v.z, sx0v.w,
                           sx1v.x, sx1v.y, sx1v.z, sx1v.w };
            #pragma unroll
            for (int f = 0; f < 2; ++f)
                #pragma unroll
                for (int r = 0; r < 4; ++r) {
                    int tt = acc_i[f][r] - zz * sxa[f * 4 + r];
                    accf[f][r] = fmaf(ss, (float)tt, accf[f][r]);
                }
            acc_i[0] = i32x4{0, 0, 0, 0};
            acc_i[1] = i32x4{0, 0, 0, 0};
        }

        // stage chunk c+1 into the other buffer (no barrier needed: private)
        if (c + 1 < NCH) WLDS(cur ^ 1, cur ^ 1);
    }

    // epilogue: C/D layout col=lane&15, row=(lane>>4)*4+reg; out += delta_m*accf
    float4 dl0 = *reinterpret_cast<const float4*>(delta + kg * 4);
    float4 dl1 = *reinterpret_cast<const float4*>(delta + 16 + kg * 4);
    const float dla[8] = { dl0.x, dl0.y, dl0.z, dl0.w, dl1.x, dl1.y, dl1.z, dl1.w };
    #pragma unroll
    for (int f = 0; f < 2; ++f)
        #pragma unroll
        for (int r = 0; r < 4; ++r) {
            const int m = f * 16 + kg * 4 + r;
            unsafeAtomicAdd(out + (size_t)m * OUT_F + n, dla[f * 4 + r] * accf[f][r]);
        }
}

extern "C" void kernel_launch(void* const* d_in, const int* in_sizes, int n_in,
                              void* d_out, int out_size, void* d_ws, size_t ws_size,
                              hipStream_t stream)
{
    const float* inp    = (const float*)d_in[0];
    const int*   qw     = (const int*)d_in[1];
    const float* scales = (const float*)d_in[2];
    const int*   qz     = (const int*)d_in[3];
    const float* bias   = (const float*)d_in[4];
    float*       out    = (float*)d_out;

    uint4* xq    = (uint4*)d_ws;                          // 128 KB
    int*   Sx    = (int*)((char*)d_ws + 131072);          // 4 KB
    float* delta = (float*)((char*)d_ws + 131072 + 4096); // 128 B

    // blocks 0..31: quantize rows + Sx + delta; blocks 32..117: out = bias
    prep_kernel<<<118, 256, 0, stream>>>(inp, bias, xq, Sx, delta, out);

    int4_gemm_i8<<<dim3(OUT_F / BN, KBS), 256, 0, stream>>>(
        xq, qw, scales, qz, Sx, delta, out);
}

// Round 13
// 31.805 us; speedup vs baseline: 4.4969x; 1.2548x over previous
//
#include <hip/hip_runtime.h>
#include <cstdint>

#define IN_F 4096
#define OUT_F 11008
#define Q_OUT 5504
#define GROUP 128
#define BATCH 32

#define KBS 16           // k-splits (gridDim.y)
#define GPB 2            // quant groups per block
#define NCH 4            // 64-k chunks per block (K=256)
#define BN 64            // output cols per block
#define BST 18           // b_lds dword stride per n-row: 16 data + 2 pad

typedef int   i32x4 __attribute__((ext_vector_type(4)));
typedef float f32x4 __attribute__((ext_vector_type(4)));

// ---------------------------------------------------------------------------
// Prep kernel, two roles by blockIdx:
//  blocks 0..31: row m: maxabs -> delta[m]; quantize x to i8 in MFMA A-frag
//    order; per-group row sums Sx[g][m] (i32, exact).
//  blocks 32..117: out[m][n] = bias[n]  (16 floats/thread; gemm atomics add)
// ---------------------------------------------------------------------------
__global__ __launch_bounds__(256)
void prep_kernel(const float* __restrict__ x,
                 const float* __restrict__ bias,
                 uint4* __restrict__ xq,     // 8192 slots of 16 i8
                 int*   __restrict__ Sx,     // [32 g][32 m]
                 float* __restrict__ delta,  // [32]
                 float* __restrict__ out)
{
    const int t = threadIdx.x;
    if (blockIdx.x >= 32) {
        const int base = (blockIdx.x - 32) * 4096 + t * 16;
        #pragma unroll
        for (int i = 0; i < 4; ++i)
            *reinterpret_cast<float4*>(out + base + i * 4) =
                *reinterpret_cast<const float4*>(bias + ((base + i * 4) % OUT_F));
        return;
    }
    const int m = blockIdx.x;
    const float* xr = x + (size_t)m * IN_F + t * 16;  // thread owns k=16t..16t+15
    float4 v[4];
    #pragma unroll
    for (int i = 0; i < 4; ++i) v[i] = reinterpret_cast<const float4*>(xr)[i];

    float lm = 0.f;
    #pragma unroll
    for (int i = 0; i < 4; ++i) {
        lm = fmaxf(lm, fmaxf(fmaxf(fabsf(v[i].x), fabsf(v[i].y)),
                             fmaxf(fabsf(v[i].z), fabsf(v[i].w))));
    }
    #pragma unroll
    for (int d = 32; d; d >>= 1) lm = fmaxf(lm, __shfl_xor(lm, d));
    __shared__ float wred[4];
    if ((t & 63) == 0) wred[t >> 6] = lm;
    __syncthreads();
    const float mx  = fmaxf(fmaxf(wred[0], wred[1]), fmaxf(wred[2], wred[3]));
    const float inv = mx > 0.f ? 127.0f / mx : 0.f;

    int q[16];
    #pragma unroll
    for (int i = 0; i < 4; ++i) {
        q[i * 4 + 0] = __float2int_rn(v[i].x * inv);
        q[i * 4 + 1] = __float2int_rn(v[i].y * inv);
        q[i * 4 + 2] = __float2int_rn(v[i].z * inv);
        q[i * 4 + 3] = __float2int_rn(v[i].w * inv);
    }
    uint4 w;
    uint* wp = reinterpret_cast<uint*>(&w);
    #pragma unroll
    for (int i = 0; i < 4; ++i)
        wp[i] = (q[i*4] & 255) | ((q[i*4+1] & 255) << 8) |
                ((q[i*4+2] & 255) << 16) | ((q[i*4+3] & 255) << 24);
    // slot = S*128 + f*64 + kg*16 + (m&15);  S=t>>2, kg=t&3, f=m>>4
    xq[(t >> 2) * 128 + (m >> 4) * 64 + (t & 3) * 16 + (m & 15)] = w;

    int psum = 0;
    #pragma unroll
    for (int i = 0; i < 16; ++i) psum += q[i];
    #pragma unroll
    for (int d = 4; d; d >>= 1) psum += __shfl_down(psum, d, 8);
    if ((t & 7) == 0) Sx[(t >> 3) * 32 + m] = psum;   // g = t>>3
    if (t == 0) delta[m] = mx * (1.0f / 127.0f);
}

// ---------------------------------------------------------------------------
// GEMM: per block M=32, N=64, K=256 (2 groups). 4 waves, each 16 cols.
// == r5 inner structure (LDS transpose, barrier discipline, MFMA math) with
//    ALL global loads hoisted to the prologue ==
// r11 PMC (MfmaUtil 2%, VALUBusy 13%, occ 34.5%) -> latency-bound, too few
// bytes in flight. Here each wave issues its ENTIRE K-slice in one burst:
// 16 B-loads (dwordx2) + 8 A-loads (dwordx4) = 256 B/lane outstanding, one
// latency exposure per block. No in-loop refills, no global_load_lds drain.
// Grid 2752 blocks (10.75/CU) for occupancy; LDS 9 KB; launch_bounds(256,4).
// Per group (2 chunks): acc_i32 -> accf += s*(D - z*Sx).
// Epilogue: out += delta_m * accf via unsafeAtomicAdd (out = bias by prep).
// ---------------------------------------------------------------------------
__global__ __launch_bounds__(256, 4)
void int4_gemm_i8(const uint4* __restrict__ xq,
                  const int*   __restrict__ qw,
                  const float* __restrict__ scales,
                  const int*   __restrict__ qz,
                  const int*   __restrict__ Sx,
                  const float* __restrict__ delta,
                  float*       __restrict__ out)
{
    const int tid  = threadIdx.x;
    const int lane = tid & 63;
    const int wid  = tid >> 6;
    const int nb   = blockIdx.x;          // 0..171
    const int kb   = blockIdx.y;          // 0..15
    const int g0   = kb * GPB;
    const int k0b  = kb * (NCH * 64);     // 256-k base

    __shared__ int b_lds[2][64 * BST];    // 2 x 4.5 KB

    const int cl  = lane & 15;
    const int kg  = lane >> 4;
    const int n   = nb * BN + wid * 16 + cl;
    const int shn = (cl & 1) * 4;

    // B staging geometry (r5): a16 = words 2a16,2a16+1; rk = rows 4rk..4rk+3
    const int a16 = tid & 15;
    const int rk  = tid >> 4;

    uint2 d[NCH][4];                      // ALL B chunks in registers
    uint4 A[NCH][2];                      // ALL A fragments in registers

    // ---- prologue: issue every global load back-to-back (max MLP) ----
    #pragma unroll
    for (int c = 0; c < NCH; ++c) {
        const int kr = k0b + c * 64 + 4 * rk;
        #pragma unroll
        for (int i = 0; i < 4; ++i)
            d[c][i] = *reinterpret_cast<const uint2*>(
                qw + (size_t)(kr + i) * Q_OUT + nb * 32 + 2 * a16);
    }
    #pragma unroll
    for (int c = 0; c < NCH; ++c) {
        const uint4* ab = xq + (size_t)(kb * NCH + c) * 128;
        A[c][0] = ab[lane];
        A[c][1] = ab[64 + lane];
    }
    int   zv[GPB];
    float sv[GPB];
    #pragma unroll
    for (int g = 0; g < GPB; ++g) {
        sv[g] = scales[(size_t)(g0 + g) * OUT_F + n];
        zv[g] = (qz[(size_t)(g0 + g) * Q_OUT + (n >> 1)] >> shn) & 15;
    }

    auto WLDS = [&](int buf, int set) {
        #pragma unroll
        for (int j = 0; j < 2; ++j) {
            // k-major dword: low bytes of 4 consecutive k-rows, word 2a16+j
            uint b0 = (j ? d[set][0].y : d[set][0].x) & 255u;
            uint b1 = (j ? d[set][1].y : d[set][1].x) & 255u;
            uint b2 = (j ? d[set][2].y : d[set][2].x) & 255u;
            uint b3 = (j ? d[set][3].y : d[set][3].x) & 255u;
            uint p  = b0 | (b1 << 8) | (b2 << 16) | (b3 << 24);
            const int nloc = 4 * a16 + 2 * j;
            b_lds[buf][(nloc + 0) * BST + rk] = (int)(p & 0x0F0F0F0Fu);
            b_lds[buf][(nloc + 1) * BST + rk] = (int)((p >> 4) & 0x0F0F0F0Fu);
        }
    };

    i32x4 acc_i[2] = {};
    f32x4 accf[2]  = {};
    int4  sx0v = {}, sx1v = {};

    WLDS(0, 0);                            // compiler waits only for d[0]
    asm volatile("s_waitcnt lgkmcnt(0)" ::: "memory");
    __builtin_amdgcn_s_barrier();
    asm volatile("" ::: "memory");

    #pragma unroll
    for (int c = 0; c < NCH; ++c) {
        const int cur = c & 1;
        const int gl  = c >> 1;
        if ((c & 1) == 0) {   // group start: fetch Sx rows (L2-hot)
            sx0v = *reinterpret_cast<const int4*>(Sx + (g0 + gl) * 32 + kg * 4);
            sx1v = *reinterpret_cast<const int4*>(Sx + (g0 + gl) * 32 + 16 + kg * 4);
        }

        // B fragment: n-row (nibble-extracted i8), dwords 4kg..4kg+3
        const int* bp = &b_lds[cur][(wid * 16 + cl) * BST + 4 * kg];
        int2 qa = *reinterpret_cast<const int2*>(bp);
        int2 qb = *reinterpret_cast<const int2*>(bp + 2);
        i32x4 bv; bv[0] = qa.x; bv[1] = qa.y; bv[2] = qb.x; bv[3] = qb.y;

        acc_i[0] = __builtin_amdgcn_mfma_i32_16x16x64_i8(
            __builtin_bit_cast(i32x4, A[c][0]), bv, acc_i[0], 0, 0, 0);
        acc_i[1] = __builtin_amdgcn_mfma_i32_16x16x64_i8(
            __builtin_bit_cast(i32x4, A[c][1]), bv, acc_i[1], 0, 0, 0);

        if (c & 1) {          // group end: integer zero-point fixup, scale
            const int   zz = zv[gl];
            const float ss = sv[gl];
            int sxa[8] = { sx0v.x, sx0v.y, sx0v.z, sx0v.w,
                           sx1v.x, sx1v.y, sx1v.z, sx1v.w };
            #pragma unroll
            for (int f = 0; f < 2; ++f)
                #pragma unroll
                for (int r = 0; r < 4; ++r) {
                    int tt = acc_i[f][r] - zz * sxa[f * 4 + r];
                    accf[f][r] = fmaf(ss, (float)tt, accf[f][r]);
                }
            acc_i[0] = i32x4{0, 0, 0, 0};
            acc_i[1] = i32x4{0, 0, 0, 0};
        }

        if (c + 1 < NCH) {
            WLDS(cur ^ 1, c + 1);          // d[c+1] already in registers
            asm volatile("s_waitcnt lgkmcnt(0)" ::: "memory");
            __builtin_amdgcn_s_barrier();
            asm volatile("" ::: "memory");
        }
    }

    // epilogue: C/D layout col=lane&15, row=(lane>>4)*4+reg; out += delta_m*accf
    float4 dl0 = *reinterpret_cast<const float4*>(delta + kg * 4);
    float4 dl1 = *reinterpret_cast<const float4*>(delta + 16 + kg * 4);
    const float dla[8] = { dl0.x, dl0.y, dl0.z, dl0.w, dl1.x, dl1.y, dl1.z, dl1.w };
    #pragma unroll
    for (int f = 0; f < 2; ++f)
        #pragma unroll
        for (int r = 0; r < 4; ++r) {
            const int m = f * 16 + kg * 4 + r;
            unsafeAtomicAdd(out + (size_t)m * OUT_F + n, dla[f * 4 + r] * accf[f][r]);
        }
}

extern "C" void kernel_launch(void* const* d_in, const int* in_sizes, int n_in,
                              void* d_out, int out_size, void* d_ws, size_t ws_size,
                              hipStream_t stream)
{
    const float* inp    = (const float*)d_in[0];
    const int*   qw     = (const int*)d_in[1];
    const float* scales = (const float*)d_in[2];
    const int*   qz     = (const int*)d_in[3];
    const float* bias   = (const float*)d_in[4];
    float*       out    = (float*)d_out;

    uint4* xq    = (uint4*)d_ws;                          // 128 KB
    int*   Sx    = (int*)((char*)d_ws + 131072);          // 4 KB
    float* delta = (float*)((char*)d_ws + 131072 + 4096); // 128 B

    // blocks 0..31: quantize rows + Sx + delta; blocks 32..117: out = bias
    prep_kernel<<<118, 256, 0, stream>>>(inp, bias, xq, Sx, delta, out);

    int4_gemm_i8<<<dim3(OUT_F / BN, KBS), 256, 0, stream>>>(
        xq, qw, scales, qz, Sx, delta, out);
}